// Round 10
// baseline (586.424 us; speedup 1.0000x reference)
//
#include <hip/hip_runtime.h>
#include <hip/hip_fp16.h>

static constexpr float NEG_SLOPE = 0.2f;
#define BUCKET_BITS 7
#define BNODES (1 << BUCKET_BITS)      // 128 nodes per bucket
#define MAXNB 1024                     // supports n <= 131072 (src fits 17 bits)
#define MAXSUP 32                      // super-buckets (dst >> 12)
#define SUPER_SHIFT 12
#define CHUNK 8192
#define PTHREADS 512

__device__ __forceinline__ float2 h2f(float r) {
  return __half22float2(__builtin_bit_cast(__half2, r));
}

// ------- Layer-1 node transform: packed x+as fp16 row (16B) + ad -----------
// Also zeroes gcount (replaces a pathologically slow 4KB hipMemsetAsync).
__global__ void k_node1(const float* __restrict__ x,
                        const float* __restrict__ w1,    // [3,32]
                        const float* __restrict__ atts,  // [2,16]
                        const float* __restrict__ attd,  // [2,16]
                        float4* __restrict__ xp,         // [N] {x0,x1,x2,as0,as1} fp16
                        float* __restrict__ ad_,         // [N,2]
                        unsigned* __restrict__ gcount,   // [MAXNB+1] zeroed here
                        int n) {
  int i = blockIdx.x * blockDim.x + threadIdx.x;
  if (i <= MAXNB) gcount[i] = 0u;
  if (i >= n) return;
  float x0 = x[3*i], x1 = x[3*i+1], x2 = x[3*i+2];
  float v[32];
#pragma unroll
  for (int j = 0; j < 32; ++j)
    v[j] = fmaf(x0, w1[j], fmaf(x1, w1[32+j], x2 * w1[64+j]));
  float s0=0.f, s1=0.f, d0=0.f, d1=0.f;
#pragma unroll
  for (int k = 0; k < 16; ++k) {
    s0 = fmaf(v[k],    atts[k],    s0);
    d0 = fmaf(v[k],    attd[k],    d0);
    s1 = fmaf(v[16+k], atts[16+k], s1);
    d1 = fmaf(v[16+k], attd[16+k], d1);
  }
  float4 r;
  r.x = __builtin_bit_cast(float, __floats2half2_rn(x0, x1));
  r.y = __builtin_bit_cast(float, __floats2half2_rn(x2, s0));
  r.z = __builtin_bit_cast(float, __floats2half2_rn(s1, 0.f));
  r.w = 0.f;
  xp[i] = r;
  ad_[2*i] = d0; ad_[2*i+1] = d1;
}

// ---------------- 1024-bin bucket histogram (single edst pass) -------------
__global__ void k_hist1024(const int* __restrict__ edst, unsigned* __restrict__ gcount,
                           int E, int nb) {
  __shared__ unsigned hist[MAXNB];
  for (int b = threadIdx.x; b < MAXNB; b += blockDim.x) hist[b] = 0u;
  __syncthreads();
  int stride = gridDim.x * blockDim.x;
  for (int e = blockIdx.x * blockDim.x + threadIdx.x; e < E; e += stride)
    atomicAdd(&hist[((unsigned)edst[e]) >> BUCKET_BITS], 1u);
  __syncthreads();
  for (int b = threadIdx.x; b < nb; b += blockDim.x)
    if (hist[b]) atomicAdd(&gcount[b], hist[b]);
}

// -------- One scan: bucket starts/cursors AND super starts/cursors ---------
__global__ void k_scanall(const unsigned* __restrict__ gcount,
                          unsigned* __restrict__ bstart, unsigned* __restrict__ bcur,
                          unsigned* __restrict__ sstart, unsigned* __restrict__ scur,
                          int nb) {
  __shared__ unsigned sm[MAXNB];
  __shared__ unsigned ex[MAXNB];
  int t = threadIdx.x;
  unsigned v = (t < nb) ? gcount[t] : 0u;
  sm[t] = v; __syncthreads();
  for (int off = 1; off < MAXNB; off <<= 1) {
    unsigned u = (t >= off) ? sm[t - off] : 0u;
    __syncthreads();
    sm[t] += u;
    __syncthreads();
  }
  unsigned excl = sm[t] - v;
  ex[t] = excl;
  bstart[t] = excl;
  if (t < nb) bcur[t] = excl;
  __syncthreads();
  if (t < MAXSUP) { unsigned e2 = ex[t << 5]; sstart[t] = e2; scur[t] = e2; }
  if (t == 0) sstart[MAXSUP] = sm[MAXNB - 1];
}

// ---------------- Pass 1: distribute edges by super (32 bins) --------------
__global__ void k_part1(const int* __restrict__ esrc, const int* __restrict__ edst,
                        unsigned* __restrict__ scur, unsigned* __restrict__ tmp1,
                        int E) {
  __shared__ unsigned shist[MAXSUP], sbase[MAXSUP], soffs[MAXSUP];
  int t = threadIdx.x;
  if (t < MAXSUP) { shist[t] = 0u; soffs[t] = 0u; }
  __syncthreads();
  int e0 = blockIdx.x * CHUNK;
  int e1 = min(E, e0 + CHUNK);
  for (int e = e0 + t; e < e1; e += PTHREADS)
    atomicAdd(&shist[((unsigned)edst[e]) >> SUPER_SHIFT], 1u);
  __syncthreads();
  if (t < MAXSUP) sbase[t] = shist[t] ? atomicAdd(&scur[t], shist[t]) : 0u;
  __syncthreads();
  for (int e = e0 + t; e < e1; e += PTHREADS) {
    unsigned d = (unsigned)edst[e];
    unsigned hi = d >> SUPER_SHIFT;
    unsigned pk = (((d >> BUCKET_BITS) & 31u) << 24)
                | ((d & (BNODES - 1u)) << 17) | (unsigned)esrc[e];
    unsigned r = atomicAdd(&soffs[hi], 1u);
    tmp1[sbase[hi] + r] = pk;
  }
}

// ---------------- Pass 2: within super, distribute by b_lo (32 bins) -------
__global__ void k_part2(const unsigned* __restrict__ tmp1,
                        const unsigned* __restrict__ sstart, // [MAXSUP+1]
                        unsigned* __restrict__ bcur,
                        unsigned* __restrict__ packed2,
                        int E, int nb) {
  __shared__ unsigned stage[CHUNK];
  __shared__ unsigned sst[MAXSUP + 1];
  __shared__ unsigned hist[4*32], base[4*32], offs[4*32];
  __shared__ int s0sh;
  int t = threadIdx.x;
  if (t <= MAXSUP) sst[t] = sstart[t];
  if (t < 128) { hist[t] = 0u; offs[t] = 0u; }
  __syncthreads();
  int e0 = blockIdx.x * CHUNK;
  int e1 = min(E, e0 + CHUNK);
  if (t == 0) {
    int s = 0;
    while (s + 1 < MAXSUP && (int)sst[s + 1] <= e0) ++s;
    s0sh = s;
  }
  __syncthreads();
  int s0 = s0sh;
  {
    int s = s0;
    for (int e = e0 + t; e < e1; e += PTHREADS) {
      while ((unsigned)e >= sst[s + 1]) ++s;
      unsigned pk = tmp1[e];
      int ds = s - s0;
      if (ds < 4) {
        atomicAdd(&hist[(ds << 5) | (pk >> 24)], 1u);
        stage[e - e0] = pk | ((unsigned)ds << 29);
      } else {
        unsigned b = ((unsigned)s << 5) | (pk >> 24);
        unsigned slot = atomicAdd(&bcur[b], 1u);
        packed2[slot] = pk & 0x00FFFFFFu;
        stage[e - e0] = 0xFFFFFFFFu;
      }
    }
  }
  __syncthreads();
  if (t < 128) {
    unsigned b = (((unsigned)(s0 + (t >> 5))) << 5) | (t & 31u);
    if (hist[t] && b < (unsigned)nb)
      base[t] = atomicAdd(&bcur[b], hist[t]);
  }
  __syncthreads();
  for (int e = e0 + t; e < e1; e += PTHREADS) {
    unsigned v = stage[e - e0];
    unsigned ds = v >> 29;
    if (ds < 4u) {
      unsigned idx = (ds << 5) | ((v >> 24) & 31u);
      unsigned r = atomicAdd(&offs[idx], 1u);
      packed2[base[idx] + r] = v & 0x00FFFFFFu;
    }
  }
}

// -------- L1 bucket gather: thread-per-edge, LDS accum (transposed) --------
// acc[k][local], k = {x0,x1,x2,den}x2heads; bank = local%32 -> ~2-way, free.
__global__ void k_bucketL1(const unsigned* __restrict__ bstart,
                           const unsigned* __restrict__ packed2,
                           const float4* __restrict__ xp,  // [N] packed 16B
                           const float* __restrict__ ad_,  // [N,2]
                           float4* __restrict__ numx,      // [N,2]
                           int n) {
  __shared__ float acc[8 * BNODES];
  __shared__ float adl[2 * BNODES];
  int b = blockIdx.x;
  int base = b << BUCKET_BITS;
  int nNodes = min(BNODES, n - base);
  int t = threadIdx.x;
  for (int i = t; i < 8 * BNODES; i += 256) acc[i] = 0.f;
  for (int i = t; i < nNodes * 2; i += 256) adl[i] = ad_[(size_t)base * 2 + i];
  __syncthreads();
  unsigned s0 = bstart[b], s1 = bstart[b + 1];
  for (unsigned j = s0 + t; j < s1; j += 256) {
    unsigned pk = packed2[j];
    unsigned s = pk & 0x1FFFFu;
    unsigned local = (pk >> 17) & 127u;
    float4 r = xp[s];
    float2 x01 = h2f(r.x);           // x0, x1
    float2 x2s = h2f(r.y);           // x2, as0
    float2 s1v = h2f(r.z);           // as1, -
    float a0 = x2s.y + adl[local*2];     a0 = (a0 >= 0.f) ? a0 : NEG_SLOPE*a0;
    float a1 = s1v.x + adl[local*2 + 1]; a1 = (a1 >= 0.f) ? a1 : NEG_SLOPE*a1;
    float e0 = __expf(a0), e1 = __expf(a1);
    atomicAdd(&acc[0*BNODES + local], x01.x * e0);
    atomicAdd(&acc[1*BNODES + local], x01.y * e0);
    atomicAdd(&acc[2*BNODES + local], x2s.x * e0);
    atomicAdd(&acc[3*BNODES + local], e0);
    atomicAdd(&acc[4*BNODES + local], x01.x * e1);
    atomicAdd(&acc[5*BNODES + local], x01.y * e1);
    atomicAdd(&acc[6*BNODES + local], x2s.x * e1);
    atomicAdd(&acc[7*BNODES + local], e1);
  }
  __syncthreads();
  for (int i = t; i < nNodes * 2; i += 256) {
    int node = i >> 1, h = i & 1;
    float4 v;
    v.x = acc[(4*h + 0)*BNODES + node];
    v.y = acc[(4*h + 1)*BNODES + node];
    v.z = acc[(4*h + 2)*BNODES + node];
    v.w = acc[(4*h + 3)*BNODES + node];
    numx[(size_t)base*2 + i] = v;
  }
}

// -- L1 finalize: reconstruct Wᵀ·numx + self-loop, ReLU, L2 transform, pack -
__global__ void k_node2(const float* __restrict__ x,     // [N,3]
                        const float4* __restrict__ numx, // [N,2]
                        const float* __restrict__ ad1,   // [N,2]
                        const float* __restrict__ w1,    // [3,32]
                        const float* __restrict__ atts1, // [2,16]
                        const float* __restrict__ b1,    // [32]
                        const float* __restrict__ w2,    // [32,14]
                        const float* __restrict__ atts2, // [2,7]
                        const float* __restrict__ attd2, // [2,7]
                        float4* __restrict__ xl2p,       // [N,2] packed head rows
                        float* __restrict__ ad2,         // [N,2]
                        int n) {
  int i = blockIdx.x * blockDim.x + threadIdx.x;
  if (i >= n) return;
  float x0 = x[3*i], x1 = x[3*i+1], x2 = x[3*i+2];
  float v[32];
#pragma unroll
  for (int j = 0; j < 32; ++j)
    v[j] = fmaf(x0, w1[j], fmaf(x1, w1[32+j], x2 * w1[64+j]));
  float s0 = 0.f, s1 = 0.f;
#pragma unroll
  for (int k = 0; k < 16; ++k) {
    s0 = fmaf(v[k],    atts1[k],    s0);
    s1 = fmaf(v[16+k], atts1[16+k], s1);
  }
  float a0 = s0 + ad1[2*i];
  float a1 = s1 + ad1[2*i+1];
  a0 = (a0 >= 0.f) ? a0 : NEG_SLOPE * a0;
  a1 = (a1 >= 0.f) ? a1 : NEG_SLOPE * a1;
  float e0 = __expf(a0), e1 = __expf(a1);
  float4 nx0 = numx[2*i], nx1 = numx[2*i+1];
  float dh0 = nx0.w + e0 + 1e-16f;
  float dh1 = nx1.w + e1 + 1e-16f;
  float inv0 = 1.f / dh0, inv1 = 1.f / dh1;
  float hbuf[32];
#pragma unroll
  for (int j = 0; j < 16; ++j) {
    float nm = fmaf(nx0.x, w1[j], fmaf(nx0.y, w1[32+j], fmaf(nx0.z, w1[64+j], e0 * v[j])));
    float t = nm * inv0 + b1[j];
    hbuf[j] = t > 0.f ? t : 0.f;
  }
#pragma unroll
  for (int j = 0; j < 16; ++j) {
    int jj = 16 + j;
    float nm = fmaf(nx1.x, w1[jj], fmaf(nx1.y, w1[32+jj], fmaf(nx1.z, w1[64+jj], e1 * v[jj])));
    float t = nm * inv1 + b1[jj];
    hbuf[jj] = t > 0.f ? t : 0.f;
  }
  float o[14];
#pragma unroll
  for (int j = 0; j < 14; ++j) o[j] = 0.f;
#pragma unroll
  for (int ch = 0; ch < 32; ++ch) {
#pragma unroll
    for (int j = 0; j < 14; ++j)
      o[j] = fmaf(hbuf[ch], w2[14*ch + j], o[j]);
  }
  float t0=0.f, t1=0.f, d0=0.f, d1=0.f;
#pragma unroll
  for (int k = 0; k < 7; ++k) {
    t0 = fmaf(o[k],   atts2[k],   t0);
    d0 = fmaf(o[k],   attd2[k],   d0);
    t1 = fmaf(o[7+k], atts2[7+k], t1);
    d1 = fmaf(o[7+k], attd2[7+k], d1);
  }
  float4 rA, rB;
  rA.x = __builtin_bit_cast(float, __floats2half2_rn(o[0], o[1]));
  rA.y = __builtin_bit_cast(float, __floats2half2_rn(o[2], o[3]));
  rA.z = __builtin_bit_cast(float, __floats2half2_rn(o[4], o[5]));
  rA.w = __builtin_bit_cast(float, __floats2half2_rn(o[6], t0));
  rB.x = __builtin_bit_cast(float, __floats2half2_rn(o[7], o[8]));
  rB.y = __builtin_bit_cast(float, __floats2half2_rn(o[9], o[10]));
  rB.z = __builtin_bit_cast(float, __floats2half2_rn(o[11], o[12]));
  rB.w = __builtin_bit_cast(float, __floats2half2_rn(o[13], t1));
  xl2p[2*i]   = rA;
  xl2p[2*i+1] = rB;
  ad2[2*i] = d0; ad2[2*i+1] = d1;
}

// -------- L2 bucket gather + fused finalize (log_softmax) ------------------
// acc[k][local]: k 0..6 = head0 ch, 7 = head0 den, 8..14 = head1 ch, 15 = den.
__global__ void k_bucketL2(const unsigned* __restrict__ bstart,
                           const unsigned* __restrict__ packed2,
                           const float4* __restrict__ xl2p, // [N,2]
                           const float* __restrict__ ad2,   // [N,2]
                           const float* __restrict__ b2,    // [7]
                           float* __restrict__ out,         // [N,7]
                           int n) {
  __shared__ float acc[16 * BNODES];
  __shared__ float adl[2 * BNODES];
  int b = blockIdx.x;
  int base = b << BUCKET_BITS;
  int nNodes = min(BNODES, n - base);
  int t = threadIdx.x;
  for (int i = t; i < 16 * BNODES; i += 256) acc[i] = 0.f;
  for (int i = t; i < nNodes * 2; i += 256) adl[i] = ad2[(size_t)base * 2 + i];
  __syncthreads();
  unsigned s0 = bstart[b], s1 = bstart[b + 1];
  for (unsigned j = s0 + t; j < s1; j += 256) {
    unsigned pk = packed2[j];
    unsigned s = pk & 0x1FFFFu;
    unsigned local = (pk >> 17) & 127u;
    float4 rA = xl2p[2*(size_t)s];
    float4 rB = xl2p[2*(size_t)s + 1];
    float2 c01 = h2f(rA.x), c23 = h2f(rA.y), c45 = h2f(rA.z), c6a = h2f(rA.w);
    float a = c6a.y + adl[local*2]; a = (a >= 0.f) ? a : NEG_SLOPE*a;
    float e = __expf(a);
    atomicAdd(&acc[0*BNODES + local], c01.x * e);
    atomicAdd(&acc[1*BNODES + local], c01.y * e);
    atomicAdd(&acc[2*BNODES + local], c23.x * e);
    atomicAdd(&acc[3*BNODES + local], c23.y * e);
    atomicAdd(&acc[4*BNODES + local], c45.x * e);
    atomicAdd(&acc[5*BNODES + local], c45.y * e);
    atomicAdd(&acc[6*BNODES + local], c6a.x * e);
    atomicAdd(&acc[7*BNODES + local], e);
    float2 d01 = h2f(rB.x), d23 = h2f(rB.y), d45 = h2f(rB.z), d6a = h2f(rB.w);
    a = d6a.y + adl[local*2 + 1]; a = (a >= 0.f) ? a : NEG_SLOPE*a;
    e = __expf(a);
    atomicAdd(&acc[ 8*BNODES + local], d01.x * e);
    atomicAdd(&acc[ 9*BNODES + local], d01.y * e);
    atomicAdd(&acc[10*BNODES + local], d23.x * e);
    atomicAdd(&acc[11*BNODES + local], d23.y * e);
    atomicAdd(&acc[12*BNODES + local], d45.x * e);
    atomicAdd(&acc[13*BNODES + local], d45.y * e);
    atomicAdd(&acc[14*BNODES + local], d6a.x * e);
    atomicAdd(&acc[15*BNODES + local], e);
  }
  __syncthreads();
  for (int i = t; i < nNodes; i += 256) {
    int node = base + i;
    float4 rA = xl2p[2*(size_t)node];
    float4 rB = xl2p[2*(size_t)node + 1];
    float2 c01 = h2f(rA.x), c23 = h2f(rA.y), c45 = h2f(rA.z), c6a = h2f(rA.w);
    float2 d01 = h2f(rB.x), d23 = h2f(rB.y), d45 = h2f(rB.z), d6a = h2f(rB.w);
    float a0 = c6a.y + adl[i*2];     a0 = (a0 >= 0.f) ? a0 : NEG_SLOPE*a0;
    float a1 = d6a.y + adl[i*2 + 1]; a1 = (a1 >= 0.f) ? a1 : NEG_SLOPE*a1;
    float e0 = __expf(a0), e1 = __expf(a1);
    float chA[7] = {c01.x, c01.y, c23.x, c23.y, c45.x, c45.y, c6a.x};
    float chB[7] = {d01.x, d01.y, d23.x, d23.y, d45.x, d45.y, d6a.x};
    float inv0 = 1.f / (acc[7*BNODES + i]  + e0 + 1e-16f);
    float inv1 = 1.f / (acc[15*BNODES + i] + e1 + 1e-16f);
    float vv[7];
#pragma unroll
    for (int c = 0; c < 7; ++c) {
      float h0 = (acc[c*BNODES + i]       + chA[c] * e0) * inv0;
      float h1 = (acc[(8 + c)*BNODES + i] + chB[c] * e1) * inv1;
      vv[c] = 0.5f * (h0 + h1) + b2[c];
    }
    float m = vv[0];
#pragma unroll
    for (int c = 1; c < 7; ++c) m = fmaxf(m, vv[c]);
    float sum = 0.f;
#pragma unroll
    for (int c = 0; c < 7; ++c) sum += __expf(vv[c] - m);
    float ls = __logf(sum);
    float* o = out + (size_t)node * 7;
#pragma unroll
    for (int c = 0; c < 7; ++c) o[c] = vv[c] - m - ls;
  }
}

extern "C" void kernel_launch(void* const* d_in, const int* in_sizes, int n_in,
                              void* d_out, int out_size, void* d_ws, size_t ws_size,
                              hipStream_t stream) {
  const float* x    = (const float*)d_in[0];
  const int*   ei   = (const int*)  d_in[1];
  const float* w1   = (const float*)d_in[2];
  const float* as1w = (const float*)d_in[3];
  const float* ad1w = (const float*)d_in[4];
  const float* b1   = (const float*)d_in[5];
  const float* w2   = (const float*)d_in[6];
  const float* as2w = (const float*)d_in[7];
  const float* ad2w = (const float*)d_in[8];
  const float* b2   = (const float*)d_in[9];
  float* out = (float*)d_out;

  const int n = in_sizes[0] / 3;
  const int E = in_sizes[1] / 2;
  const int* esrc = ei;
  const int* edst = ei + E;
  const int nb = (n + BNODES - 1) >> BUCKET_BITS;   // 782 for n=100000

  const size_t Na = ((size_t)n + 3) & ~(size_t)3;   // 16B-aligned node stride
  float* ws = (float*)d_ws;
  // workspace layout (4-byte units):
  float4* xp    = (float4*)ws;                      //  4Na
  float*  ad1   = ws + 4*Na;                        //  2Na
  float4* numx  = (float4*)(ws + 6*Na);             //  8Na
  float4* xl2p  = (float4*)(ws + 14*Na);            //  8Na
  float*  ad2   = ws + 22*Na;                       //  2Na -> 24Na
  unsigned* ctrl   = (unsigned*)(ws + 24*Na);
  unsigned* gcount = ctrl;                          // MAXNB+1
  unsigned* bstart = ctrl + (MAXNB + 1);            // MAXNB+1
  unsigned* bcur   = ctrl + 2*(MAXNB + 1);          // MAXNB+1
  unsigned* sstart = ctrl + 3*(MAXNB + 1);          // MAXSUP+1
  unsigned* scur   = sstart + (MAXSUP + 1);         // MAXSUP
  int*      pad    = (int*)(scur + MAXSUP);
  unsigned* packed2= (unsigned*)(pad);              // E
  unsigned* tmp1   = packed2 + E;                   // E

  const int nbN = (n + 255) / 256;
  const int nbC = (E + CHUNK - 1) / CHUNK;

  // k_node1 zeroes gcount (no hipMemsetAsync -- the 4KB fill cost ~43us in-graph)
  k_node1<<<nbN, 256, 0, stream>>>(x, w1, as1w, ad1w, xp, ad1, gcount, n);

  // two-level radix bucket build (shared by both layers)
  k_hist1024<<<512, 256, 0, stream>>>(edst, gcount, E, nb);
  k_scanall <<<1, MAXNB, 0, stream>>>(gcount, bstart, bcur, sstart, scur, nb);
  k_part1   <<<nbC, PTHREADS, 0, stream>>>(esrc, edst, scur, tmp1, E);
  k_part2   <<<nbC, PTHREADS, 0, stream>>>(tmp1, sstart, bcur, packed2, E, nb);

  // Layer 1: bucket-LDS gather in x-space (xp table 1.6 MB, L2-resident)
  k_bucketL1<<<nb, 256, 0, stream>>>(bstart, packed2, xp, ad1, numx, n);
  k_node2<<<nbN, 256, 0, stream>>>(x, numx, ad1, w1, as1w, b1, w2,
                                   as2w, ad2w, xl2p, ad2, n);

  // Layer 2: bucket-LDS gather + fused log_softmax (xl2p table 3.2 MB)
  k_bucketL2<<<nb, 256, 0, stream>>>(bstart, packed2, xl2p, ad2, b2, out, n);
}

// Round 11
// 161.763 us; speedup vs baseline: 3.6252x; 3.6252x over previous
//
#include <hip/hip_runtime.h>
#include <hip/hip_fp16.h>

static constexpr float NEG_SLOPE = 0.2f;
#define BUCKET_BITS 7
#define BNODES (1 << BUCKET_BITS)      // 128 nodes per bucket
#define MAXNB 1024                     // supports n <= 131072 (src fits 17 bits)
#define MAXSUP 32                      // super-buckets (dst >> 12)
#define SUPER_SHIFT 12
#define CHUNK 8192
#define PTHREADS 512
#define SORT_CAP 6144                  // bucket-edge LDS staging capacity

__device__ __forceinline__ float2 h2f(float r) {
  return __half22float2(__builtin_bit_cast(__half2, r));
}

// ------- Layer-1 node transform: packed x+as fp16 row (16B) + ad -----------
// Also zeroes gcount (replaces the pathologically slow 4KB hipMemsetAsync,
// which profiled at ~43us in-graph).
__global__ void k_node1(const float* __restrict__ x,
                        const float* __restrict__ w1,    // [3,32]
                        const float* __restrict__ atts,  // [2,16]
                        const float* __restrict__ attd,  // [2,16]
                        float4* __restrict__ xp,         // [N] {x0,x1,x2,as0,as1} fp16
                        float* __restrict__ ad_,         // [N,2]
                        unsigned* __restrict__ gcount,   // [MAXNB+1] zeroed here
                        int n) {
  int i = blockIdx.x * blockDim.x + threadIdx.x;
  if (i <= MAXNB) gcount[i] = 0u;
  if (i >= n) return;
  float x0 = x[3*i], x1 = x[3*i+1], x2 = x[3*i+2];
  float v[32];
#pragma unroll
  for (int j = 0; j < 32; ++j)
    v[j] = fmaf(x0, w1[j], fmaf(x1, w1[32+j], x2 * w1[64+j]));
  float s0=0.f, s1=0.f, d0=0.f, d1=0.f;
#pragma unroll
  for (int k = 0; k < 16; ++k) {
    s0 = fmaf(v[k],    atts[k],    s0);
    d0 = fmaf(v[k],    attd[k],    d0);
    s1 = fmaf(v[16+k], atts[16+k], s1);
    d1 = fmaf(v[16+k], attd[16+k], d1);
  }
  float4 r;
  r.x = __builtin_bit_cast(float, __floats2half2_rn(x0, x1));
  r.y = __builtin_bit_cast(float, __floats2half2_rn(x2, s0));
  r.z = __builtin_bit_cast(float, __floats2half2_rn(s1, 0.f));
  r.w = 0.f;
  xp[i] = r;
  ad_[2*i] = d0; ad_[2*i+1] = d1;
}

// ---------------- 1024-bin bucket histogram (single edst pass) -------------
__global__ void k_hist1024(const int* __restrict__ edst, unsigned* __restrict__ gcount,
                           int E, int nb) {
  __shared__ unsigned hist[MAXNB];
  for (int b = threadIdx.x; b < MAXNB; b += blockDim.x) hist[b] = 0u;
  __syncthreads();
  int stride = gridDim.x * blockDim.x;
  for (int e = blockIdx.x * blockDim.x + threadIdx.x; e < E; e += stride)
    atomicAdd(&hist[((unsigned)edst[e]) >> BUCKET_BITS], 1u);
  __syncthreads();
  for (int b = threadIdx.x; b < nb; b += blockDim.x)
    if (hist[b]) atomicAdd(&gcount[b], hist[b]);
}

// -------- One scan: bucket starts/cursors AND super starts/cursors ---------
__global__ void k_scanall(const unsigned* __restrict__ gcount,
                          unsigned* __restrict__ bstart, unsigned* __restrict__ bcur,
                          unsigned* __restrict__ sstart, unsigned* __restrict__ scur,
                          int nb) {
  __shared__ unsigned sm[MAXNB];
  __shared__ unsigned ex[MAXNB];
  int t = threadIdx.x;
  unsigned v = (t < nb) ? gcount[t] : 0u;
  sm[t] = v; __syncthreads();
  for (int off = 1; off < MAXNB; off <<= 1) {
    unsigned u = (t >= off) ? sm[t - off] : 0u;
    __syncthreads();
    sm[t] += u;
    __syncthreads();
  }
  unsigned excl = sm[t] - v;
  ex[t] = excl;
  bstart[t] = excl;
  if (t < nb) bcur[t] = excl;
  __syncthreads();
  if (t < MAXSUP) { unsigned e2 = ex[t << 5]; sstart[t] = e2; scur[t] = e2; }
  if (t == 0) sstart[MAXSUP] = sm[MAXNB - 1];
}

// ---------------- Pass 1: distribute edges by super (32 bins) --------------
__global__ void k_part1(const int* __restrict__ esrc, const int* __restrict__ edst,
                        unsigned* __restrict__ scur, unsigned* __restrict__ tmp1,
                        int E) {
  __shared__ unsigned shist[MAXSUP], sbase[MAXSUP], soffs[MAXSUP];
  int t = threadIdx.x;
  if (t < MAXSUP) { shist[t] = 0u; soffs[t] = 0u; }
  __syncthreads();
  int e0 = blockIdx.x * CHUNK;
  int e1 = min(E, e0 + CHUNK);
  for (int e = e0 + t; e < e1; e += PTHREADS)
    atomicAdd(&shist[((unsigned)edst[e]) >> SUPER_SHIFT], 1u);
  __syncthreads();
  if (t < MAXSUP) sbase[t] = shist[t] ? atomicAdd(&scur[t], shist[t]) : 0u;
  __syncthreads();
  for (int e = e0 + t; e < e1; e += PTHREADS) {
    unsigned d = (unsigned)edst[e];
    unsigned hi = d >> SUPER_SHIFT;
    unsigned pk = (((d >> BUCKET_BITS) & 31u) << 24)
                | ((d & (BNODES - 1u)) << 17) | (unsigned)esrc[e];
    unsigned r = atomicAdd(&soffs[hi], 1u);
    tmp1[sbase[hi] + r] = pk;
  }
}

// ---------------- Pass 2: within super, distribute by b_lo (32 bins) -------
__global__ void k_part2(const unsigned* __restrict__ tmp1,
                        const unsigned* __restrict__ sstart, // [MAXSUP+1]
                        unsigned* __restrict__ bcur,
                        unsigned* __restrict__ packed2,
                        int E, int nb) {
  __shared__ unsigned stage[CHUNK];
  __shared__ unsigned sst[MAXSUP + 1];
  __shared__ unsigned hist[4*32], base[4*32], offs[4*32];
  __shared__ int s0sh;
  int t = threadIdx.x;
  if (t <= MAXSUP) sst[t] = sstart[t];
  if (t < 128) { hist[t] = 0u; offs[t] = 0u; }
  __syncthreads();
  int e0 = blockIdx.x * CHUNK;
  int e1 = min(E, e0 + CHUNK);
  if (t == 0) {
    int s = 0;
    while (s + 1 < MAXSUP && (int)sst[s + 1] <= e0) ++s;
    s0sh = s;
  }
  __syncthreads();
  int s0 = s0sh;
  {
    int s = s0;
    for (int e = e0 + t; e < e1; e += PTHREADS) {
      while ((unsigned)e >= sst[s + 1]) ++s;
      unsigned pk = tmp1[e];
      int ds = s - s0;
      if (ds < 4) {
        atomicAdd(&hist[(ds << 5) | (pk >> 24)], 1u);
        stage[e - e0] = pk | ((unsigned)ds << 29);
      } else {
        unsigned b = ((unsigned)s << 5) | (pk >> 24);
        unsigned slot = atomicAdd(&bcur[b], 1u);
        packed2[slot] = pk & 0x00FFFFFFu;
        stage[e - e0] = 0xFFFFFFFFu;
      }
    }
  }
  __syncthreads();
  if (t < 128) {
    unsigned b = (((unsigned)(s0 + (t >> 5))) << 5) | (t & 31u);
    if (hist[t] && b < (unsigned)nb)
      base[t] = atomicAdd(&bcur[b], hist[t]);
  }
  __syncthreads();
  for (int e = e0 + t; e < e1; e += PTHREADS) {
    unsigned v = stage[e - e0];
    unsigned ds = v >> 29;
    if (ds < 4u) {
      unsigned idx = (ds << 5) | ((v >> 24) & 31u);
      unsigned r = atomicAdd(&offs[idx], 1u);
      packed2[base[idx] + r] = v & 0x00FFFFFFu;
    }
  }
}

// ---------------- Per-bucket LDS sort: bucket run -> node-sorted col + rp --
__global__ void k_sortb(const unsigned* __restrict__ bstart,
                        const unsigned* __restrict__ packed,
                        int* __restrict__ col,
                        unsigned* __restrict__ rp,
                        int n) {
  __shared__ unsigned stage_in[SORT_CAP];
  __shared__ unsigned stage_out[SORT_CAP];
  __shared__ unsigned cnt[BNODES], sm[BNODES], excl[BNODES], off[BNODES];
  int b = blockIdx.x;
  unsigned s0 = bstart[b], s1 = bstart[b + 1];
  int size = (int)(s1 - s0);
  int t = threadIdx.x;
  if (t < BNODES) cnt[t] = 0u;
  __syncthreads();
  bool lds_path = (size <= SORT_CAP);
  if (lds_path) {
    for (int i = t; i < size; i += blockDim.x) {
      unsigned pk = packed[s0 + i];
      stage_in[i] = pk;
      atomicAdd(&cnt[pk >> 17], 1u);
    }
  } else {
    for (int i = t; i < size; i += blockDim.x)
      atomicAdd(&cnt[packed[s0 + i] >> 17], 1u);
  }
  __syncthreads();
  if (t < BNODES) sm[t] = cnt[t];
  __syncthreads();
#pragma unroll
  for (int offi = 1; offi < BNODES; offi <<= 1) {
    unsigned u = (t < BNODES && t >= offi) ? sm[t - offi] : 0u;
    __syncthreads();
    if (t < BNODES) sm[t] += u;
    __syncthreads();
  }
  if (t < BNODES) { excl[t] = sm[t] - cnt[t]; off[t] = sm[t] - cnt[t]; }
  __syncthreads();
  if (lds_path) {
    for (int i = t; i < size; i += blockDim.x) {
      unsigned pk = stage_in[i];
      unsigned slot = atomicAdd(&off[pk >> 17], 1u);
      stage_out[slot] = pk & 0x1FFFFu;
    }
    __syncthreads();
    for (int i = t; i < size; i += blockDim.x)
      col[s0 + i] = (int)stage_out[i];
  } else {
    for (int i = t; i < size; i += blockDim.x) {
      unsigned pk = packed[s0 + i];
      unsigned slot = atomicAdd(&off[pk >> 17], 1u);
      col[s0 + slot] = (int)(pk & 0x1FFFFu);
    }
  }
  int base = b << BUCKET_BITS;
  if (t < BNODES && base + t < n) rp[base + t] = s0 + excl[t];
}

// ------ Layer-1 gather in x-space: 1 lane/node, both heads, unroll 4 ------
// numx[2d+h] = {Σ e_h x0, Σ e_h x1, Σ e_h x2, Σ e_h} over real edges only.
__global__ void k_gatherX(const unsigned* __restrict__ rp,
                          const int* __restrict__ col,
                          const float4* __restrict__ xp,  // [N] packed 16B
                          const float* __restrict__ ad_,  // [N,2]
                          float4* __restrict__ numx,      // [N,2]
                          int n, int E) {
  int d = blockIdx.x * blockDim.x + threadIdx.x;
  if (d >= n) return;
  float ad0 = ad_[2*d], ad1v = ad_[2*d+1];
  float4 a0 = make_float4(0.f,0.f,0.f,0.f);
  float4 a1 = make_float4(0.f,0.f,0.f,0.f);
  unsigned jb = rp[d];
  unsigned je = (d + 1 < n) ? rp[d + 1] : (unsigned)E;
  unsigned j = jb;

  auto proc = [&](float4 r) {
    float2 fx01 = h2f(r.x);          // x0, x1
    float2 fx2s = h2f(r.y);          // x2, as0
    float2 fs1  = h2f(r.z);          // as1, -
    float a = fx2s.y + ad0; a = (a >= 0.f) ? a : NEG_SLOPE*a;
    float e0 = __expf(a);
    a = fs1.x + ad1v; a = (a >= 0.f) ? a : NEG_SLOPE*a;
    float e1 = __expf(a);
    a0.x = fmaf(fx01.x, e0, a0.x); a0.y = fmaf(fx01.y, e0, a0.y);
    a0.z = fmaf(fx2s.x, e0, a0.z); a0.w += e0;
    a1.x = fmaf(fx01.x, e1, a1.x); a1.y = fmaf(fx01.y, e1, a1.y);
    a1.z = fmaf(fx2s.x, e1, a1.z); a1.w += e1;
  };

  for (; j + 4 <= je; j += 4) {
    int s0 = col[j], s1 = col[j+1], s2 = col[j+2], s3 = col[j+3];
    float4 r0 = xp[s0], r1 = xp[s1], r2 = xp[s2], r3 = xp[s3];
    proc(r0); proc(r1); proc(r2); proc(r3);
  }
  for (; j < je; ++j) proc(xp[col[j]]);
  numx[2*d]   = a0;
  numx[2*d+1] = a1;
}

// -- L1 finalize: reconstruct Wᵀ·numx + self-loop, ReLU, L2 transform, pack -
__global__ void k_node2(const float* __restrict__ x,     // [N,3]
                        const float4* __restrict__ numx, // [N,2]
                        const float* __restrict__ ad1,   // [N,2]
                        const float* __restrict__ w1,    // [3,32]
                        const float* __restrict__ atts1, // [2,16]
                        const float* __restrict__ b1,    // [32]
                        const float* __restrict__ w2,    // [32,14]
                        const float* __restrict__ atts2, // [2,7]
                        const float* __restrict__ attd2, // [2,7]
                        float4* __restrict__ xl2p,       // [N,2] packed head rows
                        float* __restrict__ ad2,         // [N,2]
                        int n) {
  int i = blockIdx.x * blockDim.x + threadIdx.x;
  if (i >= n) return;
  float x0 = x[3*i], x1 = x[3*i+1], x2 = x[3*i+2];
  float v[32];
#pragma unroll
  for (int j = 0; j < 32; ++j)
    v[j] = fmaf(x0, w1[j], fmaf(x1, w1[32+j], x2 * w1[64+j]));
  float s0 = 0.f, s1 = 0.f;
#pragma unroll
  for (int k = 0; k < 16; ++k) {
    s0 = fmaf(v[k],    atts1[k],    s0);
    s1 = fmaf(v[16+k], atts1[16+k], s1);
  }
  float a0 = s0 + ad1[2*i];
  float a1 = s1 + ad1[2*i+1];
  a0 = (a0 >= 0.f) ? a0 : NEG_SLOPE * a0;
  a1 = (a1 >= 0.f) ? a1 : NEG_SLOPE * a1;
  float e0 = __expf(a0), e1 = __expf(a1);
  float4 nx0 = numx[2*i], nx1 = numx[2*i+1];
  float dh0 = nx0.w + e0 + 1e-16f;
  float dh1 = nx1.w + e1 + 1e-16f;
  float inv0 = 1.f / dh0, inv1 = 1.f / dh1;
  float hbuf[32];
#pragma unroll
  for (int j = 0; j < 16; ++j) {
    float nm = fmaf(nx0.x, w1[j], fmaf(nx0.y, w1[32+j], fmaf(nx0.z, w1[64+j], e0 * v[j])));
    float t = nm * inv0 + b1[j];
    hbuf[j] = t > 0.f ? t : 0.f;
  }
#pragma unroll
  for (int j = 0; j < 16; ++j) {
    int jj = 16 + j;
    float nm = fmaf(nx1.x, w1[jj], fmaf(nx1.y, w1[32+jj], fmaf(nx1.z, w1[64+jj], e1 * v[jj])));
    float t = nm * inv1 + b1[jj];
    hbuf[jj] = t > 0.f ? t : 0.f;
  }
  float o[14];
#pragma unroll
  for (int j = 0; j < 14; ++j) o[j] = 0.f;
#pragma unroll
  for (int ch = 0; ch < 32; ++ch) {
#pragma unroll
    for (int j = 0; j < 14; ++j)
      o[j] = fmaf(hbuf[ch], w2[14*ch + j], o[j]);
  }
  float t0=0.f, t1=0.f, d0=0.f, d1=0.f;
#pragma unroll
  for (int k = 0; k < 7; ++k) {
    t0 = fmaf(o[k],   atts2[k],   t0);
    d0 = fmaf(o[k],   attd2[k],   d0);
    t1 = fmaf(o[7+k], atts2[7+k], t1);
    d1 = fmaf(o[7+k], attd2[7+k], d1);
  }
  // head rows: {o0..o6, as2_h} packed fp16 into one float4 each
  float4 rA, rB;
  rA.x = __builtin_bit_cast(float, __floats2half2_rn(o[0], o[1]));
  rA.y = __builtin_bit_cast(float, __floats2half2_rn(o[2], o[3]));
  rA.z = __builtin_bit_cast(float, __floats2half2_rn(o[4], o[5]));
  rA.w = __builtin_bit_cast(float, __floats2half2_rn(o[6], t0));
  rB.x = __builtin_bit_cast(float, __floats2half2_rn(o[7], o[8]));
  rB.y = __builtin_bit_cast(float, __floats2half2_rn(o[9], o[10]));
  rB.z = __builtin_bit_cast(float, __floats2half2_rn(o[11], o[12]));
  rB.w = __builtin_bit_cast(float, __floats2half2_rn(o[13], t1));
  xl2p[2*i]   = rA;
  xl2p[2*i+1] = rB;
  ad2[2*i] = d0; ad2[2*i+1] = d1;
}

// -- L2 gather + finalize: 2 lanes/node (1 per head), as packed in row ------
__global__ void k_gather_final(const unsigned* __restrict__ rp,
                               const int* __restrict__ col,
                               const float4* __restrict__ xl2p, // [N,2]
                               const float* __restrict__ ad2,   // [N,2]
                               const float* __restrict__ b2,    // [7]
                               float* __restrict__ out,         // [N,7]
                               int n, int E) {
  int idx = blockIdx.x * blockDim.x + threadIdx.x;
  int d = idx >> 1;
  int h = idx & 1;
  if (d >= n) return;
  float adh = ad2[2*d + h];
  float acc[7] = {0.f,0.f,0.f,0.f,0.f,0.f,0.f};
  float den = 0.f;

  auto proc = [&](float4 r) {
    float2 c01 = h2f(r.x), c23 = h2f(r.y), c45 = h2f(r.z), c6a = h2f(r.w);
    float a = c6a.y + adh; a = (a >= 0.f) ? a : NEG_SLOPE*a;
    float e = __expf(a);
    acc[0] = fmaf(c01.x, e, acc[0]); acc[1] = fmaf(c01.y, e, acc[1]);
    acc[2] = fmaf(c23.x, e, acc[2]); acc[3] = fmaf(c23.y, e, acc[3]);
    acc[4] = fmaf(c45.x, e, acc[4]); acc[5] = fmaf(c45.y, e, acc[5]);
    acc[6] = fmaf(c6a.x, e, acc[6]); den += e;
  };

  unsigned jb = rp[d];
  unsigned je = (d + 1 < n) ? rp[d + 1] : (unsigned)E;
  unsigned j = jb;
  for (; j + 4 <= je; j += 4) {
    int s0 = col[j], s1 = col[j+1], s2 = col[j+2], s3 = col[j+3];
    float4 r0 = xl2p[2*(size_t)s0 + h];
    float4 r1 = xl2p[2*(size_t)s1 + h];
    float4 r2 = xl2p[2*(size_t)s2 + h];
    float4 r3 = xl2p[2*(size_t)s3 + h];
    proc(r0); proc(r1); proc(r2); proc(r3);
  }
  for (; j < je; ++j) proc(xl2p[2*(size_t)col[j] + h]);
  proc(xl2p[2*(size_t)d + h]);   // self-loop

  float inv = 1.f / (den + 1e-16f);
  float v[7];
#pragma unroll
  for (int c = 0; c < 7; ++c) {
    float mine = acc[c] * inv;
    float other = __shfl_xor(mine, 1, 2);      // other head, same node
    v[c] = 0.5f * (mine + other) + b2[c];
  }
  float m = v[0];
#pragma unroll
  for (int c = 1; c < 7; ++c) m = fmaxf(m, v[c]);
  float s = 0.f;
#pragma unroll
  for (int c = 0; c < 7; ++c) s += __expf(v[c] - m);
  float ls = __logf(s);
  float* o = out + (size_t)d * 7;
  if (h == 0) {
    o[0] = v[0]-m-ls; o[1] = v[1]-m-ls; o[2] = v[2]-m-ls; o[3] = v[3]-m-ls;
  } else {
    o[4] = v[4]-m-ls; o[5] = v[5]-m-ls; o[6] = v[6]-m-ls;
  }
}

extern "C" void kernel_launch(void* const* d_in, const int* in_sizes, int n_in,
                              void* d_out, int out_size, void* d_ws, size_t ws_size,
                              hipStream_t stream) {
  const float* x    = (const float*)d_in[0];
  const int*   ei   = (const int*)  d_in[1];
  const float* w1   = (const float*)d_in[2];
  const float* as1w = (const float*)d_in[3];
  const float* ad1w = (const float*)d_in[4];
  const float* b1   = (const float*)d_in[5];
  const float* w2   = (const float*)d_in[6];
  const float* as2w = (const float*)d_in[7];
  const float* ad2w = (const float*)d_in[8];
  const float* b2   = (const float*)d_in[9];
  float* out = (float*)d_out;

  const int n = in_sizes[0] / 3;
  const int E = in_sizes[1] / 2;
  const int* esrc = ei;
  const int* edst = ei + E;
  const int nb = (n + BNODES - 1) >> BUCKET_BITS;   // 782 for n=100000

  const size_t Na = ((size_t)n + 3) & ~(size_t)3;   // 16B-aligned node stride
  float* ws = (float*)d_ws;
  // workspace layout (4-byte units):
  float4* xp    = (float4*)ws;                      //  4Na  packed x+as rows
  float*  ad1   = ws + 4*Na;                        //  2Na
  float4* numx  = (float4*)(ws + 6*Na);             //  8Na
  float4* xl2p  = (float4*)(ws + 14*Na);            //  8Na
  float*  ad2   = ws + 22*Na;                       //  2Na -> 24Na
  unsigned* ctrl   = (unsigned*)(ws + 24*Na);
  unsigned* gcount = ctrl;                          // MAXNB+1
  unsigned* bstart = ctrl + (MAXNB + 1);            // MAXNB+1
  unsigned* bcur   = ctrl + 2*(MAXNB + 1);          // MAXNB+1
  unsigned* sstart = ctrl + 3*(MAXNB + 1);          // MAXSUP+1
  unsigned* scur   = sstart + (MAXSUP + 1);         // MAXSUP
  unsigned* rp     = scur + MAXSUP;                 // Na
  int*      col    = (int*)(rp + Na);               // E
  unsigned* packed2= (unsigned*)(col + E);          // E
  unsigned* tmp1   = packed2 + E;                   // E

  const int nbN = (n + 255) / 256;
  const int nbC = (E + CHUNK - 1) / CHUNK;

  // k_node1 zeroes gcount (no hipMemsetAsync -- the 4KB fill cost ~43us in-graph)
  k_node1<<<nbN, 256, 0, stream>>>(x, w1, as1w, ad1w, xp, ad1, gcount, n);

  // two-level radix CSR build (shared by both layers)
  k_hist1024<<<512, 256, 0, stream>>>(edst, gcount, E, nb);
  k_scanall <<<1, MAXNB, 0, stream>>>(gcount, bstart, bcur, sstart, scur, nb);
  k_part1   <<<nbC, PTHREADS, 0, stream>>>(esrc, edst, scur, tmp1, E);
  k_part2   <<<nbC, PTHREADS, 0, stream>>>(tmp1, sstart, bcur, packed2, E, nb);
  k_sortb   <<<nb, 256, 0, stream>>>(bstart, packed2, col, rp, n);

  // Layer 1: x-space gather, 1 lane/node, both heads (table 1.6 MB, L2-resident)
  k_gatherX<<<nbN, 256, 0, stream>>>(rp, col, xp, ad1, numx, n, E);
  k_node2<<<nbN, 256, 0, stream>>>(x, numx, ad1, w1, as1w, b1, w2,
                                   as2w, ad2w, xl2p, ad2, n);

  // Layer 2: 2 lanes/node (1 per head), as packed in row (table 3.2 MB)
  k_gather_final<<<(2*n + 255)/256, 256, 0, stream>>>(
      rp, col, xl2p, ad2, b2, out, n, E);
}

// Round 12
// 148.966 us; speedup vs baseline: 3.9366x; 1.0859x over previous
//
#include <hip/hip_runtime.h>
#include <hip/hip_fp16.h>

static constexpr float NEG_SLOPE = 0.2f;
#define BUCKET_BITS 7
#define BNODES (1 << BUCKET_BITS)      // 128 nodes per bucket
#define MAXNB 1024                     // supports n <= 131072 (src fits 17 bits)
#define MAXSUP 32                      // super-buckets (dst >> 12)
#define SUPER_SHIFT 12
#define CHUNK 4096
#define PTHREADS 256
#define SORT_CAP 6144                  // bucket-edge LDS staging capacity

__device__ __forceinline__ float2 h2f(float r) {
  return __half22float2(__builtin_bit_cast(__half2, r));
}

// ------- Layer-1 node transform: packed x+as fp16 row (16B) + ad -----------
// Also zeroes gcount (in-kernel; avoids a hipMemsetAsync launch).
__global__ void k_node1(const float* __restrict__ x,
                        const float* __restrict__ w1,    // [3,32]
                        const float* __restrict__ atts,  // [2,16]
                        const float* __restrict__ attd,  // [2,16]
                        float4* __restrict__ xp,         // [N] {x0,x1,x2,as0,as1} fp16
                        float* __restrict__ ad_,         // [N,2]
                        unsigned* __restrict__ gcount,   // [MAXNB+1] zeroed here
                        int n) {
  int i = blockIdx.x * blockDim.x + threadIdx.x;
  if (i <= MAXNB) gcount[i] = 0u;
  if (i >= n) return;
  float x0 = x[3*i], x1 = x[3*i+1], x2 = x[3*i+2];
  float v[32];
#pragma unroll
  for (int j = 0; j < 32; ++j)
    v[j] = fmaf(x0, w1[j], fmaf(x1, w1[32+j], x2 * w1[64+j]));
  float s0=0.f, s1=0.f, d0=0.f, d1=0.f;
#pragma unroll
  for (int k = 0; k < 16; ++k) {
    s0 = fmaf(v[k],    atts[k],    s0);
    d0 = fmaf(v[k],    attd[k],    d0);
    s1 = fmaf(v[16+k], atts[16+k], s1);
    d1 = fmaf(v[16+k], attd[16+k], d1);
  }
  float4 r;
  r.x = __builtin_bit_cast(float, __floats2half2_rn(x0, x1));
  r.y = __builtin_bit_cast(float, __floats2half2_rn(x2, s0));
  r.z = __builtin_bit_cast(float, __floats2half2_rn(s1, 0.f));
  r.w = 0.f;
  xp[i] = r;
  ad_[2*i] = d0; ad_[2*i+1] = d1;
}

// ---------------- 1024-bin bucket histogram (single edst pass) -------------
__global__ void k_hist1024(const int* __restrict__ edst, unsigned* __restrict__ gcount,
                           int E, int nb) {
  __shared__ unsigned hist[MAXNB];
  for (int b = threadIdx.x; b < MAXNB; b += blockDim.x) hist[b] = 0u;
  __syncthreads();
  int stride = gridDim.x * blockDim.x;
  for (int e = blockIdx.x * blockDim.x + threadIdx.x; e < E; e += stride)
    atomicAdd(&hist[((unsigned)edst[e]) >> BUCKET_BITS], 1u);
  __syncthreads();
  for (int b = threadIdx.x; b < nb; b += blockDim.x)
    if (hist[b]) atomicAdd(&gcount[b], hist[b]);
}

// -------- One scan (shfl-based): bucket starts/cursors AND super starts ----
__global__ void k_scanall(const unsigned* __restrict__ gcount,
                          unsigned* __restrict__ bstart, unsigned* __restrict__ bcur,
                          unsigned* __restrict__ sstart, unsigned* __restrict__ scur,
                          int nb) {
  __shared__ unsigned wsum[16];
  __shared__ unsigned exls[MAXNB];
  int t = threadIdx.x;                    // 1024 threads
  unsigned v = (t < nb) ? gcount[t] : 0u;
  unsigned s = v;
#pragma unroll
  for (int off = 1; off < 64; off <<= 1) {
    unsigned u = (unsigned)__shfl_up((int)s, off, 64);
    if ((t & 63) >= off) s += u;
  }
  if ((t & 63) == 63) wsum[t >> 6] = s;
  __syncthreads();
  if (t < 16) {
    unsigned w = wsum[t];
#pragma unroll
    for (int off = 1; off < 16; off <<= 1) {
      unsigned u = (unsigned)__shfl_up((int)w, off, 16);
      if (t >= off) w += u;
    }
    wsum[t] = w;                          // inclusive wave sums
  }
  __syncthreads();
  unsigned incl = s + ((t >> 6) ? wsum[(t >> 6) - 1] : 0u);
  unsigned excl = incl - v;
  exls[t] = excl;
  bstart[t] = excl;
  if (t < nb) bcur[t] = excl;
  __syncthreads();
  if (t < MAXSUP) { unsigned e2 = exls[t << 5]; sstart[t] = e2; scur[t] = e2; }
  if (t == 1023) { sstart[MAXSUP] = incl; bstart[MAXNB] = incl; }
}

// ---------------- Pass 1: distribute edges by super (32 bins) --------------
__global__ void k_part1(const int* __restrict__ esrc, const int* __restrict__ edst,
                        unsigned* __restrict__ scur, unsigned* __restrict__ tmp1,
                        int E) {
  __shared__ unsigned shist[MAXSUP], sbase[MAXSUP], soffs[MAXSUP];
  int t = threadIdx.x;
  if (t < MAXSUP) { shist[t] = 0u; soffs[t] = 0u; }
  __syncthreads();
  int e0 = blockIdx.x * CHUNK;
  int e1 = min(E, e0 + CHUNK);
  for (int e = e0 + t; e < e1; e += PTHREADS)
    atomicAdd(&shist[((unsigned)edst[e]) >> SUPER_SHIFT], 1u);
  __syncthreads();
  if (t < MAXSUP) sbase[t] = shist[t] ? atomicAdd(&scur[t], shist[t]) : 0u;
  __syncthreads();
  for (int e = e0 + t; e < e1; e += PTHREADS) {
    unsigned d = (unsigned)edst[e];
    unsigned hi = d >> SUPER_SHIFT;
    unsigned pk = (((d >> BUCKET_BITS) & 31u) << 24)
                | ((d & (BNODES - 1u)) << 17) | (unsigned)esrc[e];
    unsigned r = atomicAdd(&soffs[hi], 1u);
    tmp1[sbase[hi] + r] = pk;
  }
}

// ---------------- Pass 2: within super, distribute by b_lo (32 bins) -------
__global__ void k_part2(const unsigned* __restrict__ tmp1,
                        const unsigned* __restrict__ sstart, // [MAXSUP+1]
                        unsigned* __restrict__ bcur,
                        unsigned* __restrict__ packed2,
                        int E, int nb) {
  __shared__ unsigned stage[CHUNK];
  __shared__ unsigned sst[MAXSUP + 1];
  __shared__ unsigned hist[4*32], base[4*32], offs[4*32];
  __shared__ int s0sh;
  int t = threadIdx.x;
  if (t <= MAXSUP) sst[t] = sstart[t];
  if (t < 128) { hist[t] = 0u; offs[t] = 0u; }
  __syncthreads();
  int e0 = blockIdx.x * CHUNK;
  int e1 = min(E, e0 + CHUNK);
  if (t == 0) {
    int s = 0;
    while (s + 1 < MAXSUP && (int)sst[s + 1] <= e0) ++s;
    s0sh = s;
  }
  __syncthreads();
  int s0 = s0sh;
  {
    int s = s0;
    for (int e = e0 + t; e < e1; e += PTHREADS) {
      while ((unsigned)e >= sst[s + 1]) ++s;
      unsigned pk = tmp1[e];
      int ds = s - s0;
      if (ds < 4) {
        atomicAdd(&hist[(ds << 5) | (pk >> 24)], 1u);
        stage[e - e0] = pk | ((unsigned)ds << 29);
      } else {
        unsigned b = ((unsigned)s << 5) | (pk >> 24);
        unsigned slot = atomicAdd(&bcur[b], 1u);
        packed2[slot] = pk & 0x00FFFFFFu;
        stage[e - e0] = 0xFFFFFFFFu;
      }
    }
  }
  __syncthreads();
  if (t < 128) {
    unsigned b = (((unsigned)(s0 + (t >> 5))) << 5) | (t & 31u);
    if (hist[t] && b < (unsigned)nb)
      base[t] = atomicAdd(&bcur[b], hist[t]);
  }
  __syncthreads();
  for (int e = e0 + t; e < e1; e += PTHREADS) {
    unsigned v = stage[e - e0];
    unsigned ds = v >> 29;
    if (ds < 4u) {
      unsigned idx = (ds << 5) | ((v >> 24) & 31u);
      unsigned r = atomicAdd(&offs[idx], 1u);
      packed2[base[idx] + r] = v & 0x00FFFFFFu;
    }
  }
}

// --- Per-bucket sort + FUSED layer-1 x-space gather -------------------------
// Phase A: counting sort of the bucket's edges into stage_out (node-sorted).
// Phase B: write col+rp for the layer-2 gather.
// Phase C: 2 threads/node (node,head) walk the in-LDS edge list, gather xp
//          rows (L2-resident, 1.6 MB) and write numx directly. No col re-read.
__global__ void k_sortb_g1(const unsigned* __restrict__ bstart,
                           const unsigned* __restrict__ packed2,
                           const float4* __restrict__ xp,   // [N] packed 16B
                           const float* __restrict__ ad_,   // [N,2]
                           int* __restrict__ col,
                           unsigned* __restrict__ rp,
                           float4* __restrict__ numx,       // [N,2]
                           int n) {
  __shared__ unsigned stage_out[SORT_CAP];
  __shared__ unsigned cnt[BNODES], smi[BNODES], excl[BNODES], off[BNODES];
  int b = blockIdx.x;
  unsigned s0 = bstart[b], s1 = bstart[b + 1];
  int size = (int)(s1 - s0);
  int base = b << BUCKET_BITS;
  int nNodes = min(BNODES, n - base);
  int t = threadIdx.x;
  if (t < BNODES) cnt[t] = 0u;
  __syncthreads();
  bool lds_path = (size <= SORT_CAP);
  for (int i = t; i < size; i += 256)
    atomicAdd(&cnt[(packed2[s0 + i] >> 17) & 127u], 1u);
  __syncthreads();
  if (t < BNODES) smi[t] = cnt[t];
  __syncthreads();
#pragma unroll
  for (int offi = 1; offi < BNODES; offi <<= 1) {
    unsigned u = (t < BNODES && t >= offi) ? smi[t - offi] : 0u;
    __syncthreads();
    if (t < BNODES) smi[t] += u;
    __syncthreads();
  }
  if (t < BNODES) { unsigned e = smi[t] - cnt[t]; excl[t] = e; off[t] = e; }
  __syncthreads();
  if (lds_path) {
    for (int i = t; i < size; i += 256) {
      unsigned pk = packed2[s0 + i];        // L2-hot re-read
      unsigned slot = atomicAdd(&off[(pk >> 17) & 127u], 1u);
      stage_out[slot] = pk & 0x1FFFFu;
    }
  } else {                                  // never expected (max bucket ~4400)
    for (int i = t; i < size; i += 256) {
      unsigned pk = packed2[s0 + i];
      unsigned slot = atomicAdd(&off[(pk >> 17) & 127u], 1u);
      col[s0 + slot] = (int)(pk & 0x1FFFFu);
    }
  }
  __syncthreads();
  if (lds_path)
    for (int i = t; i < size; i += 256) col[s0 + i] = (int)stage_out[i];
  if (t < nNodes) rp[base + t] = s0 + excl[t];
  // ---- Phase C: layer-1 gather, t = node*2 + h ----
  int node = t >> 1, h = t & 1;
  if (node >= nNodes) return;
  float adh = ad_[(size_t)(base + node) * 2 + h];
  unsigned kb = excl[node], ke = kb + cnt[node];
  float4 acc = make_float4(0.f, 0.f, 0.f, 0.f);
  auto procr = [&](float4 r) {
    float2 fx01 = h2f(r.x);                 // x0, x1
    float2 fx2s = h2f(r.y);                 // x2, as0
    float2 fs1  = h2f(r.z);                 // as1, -
    float as = h ? fs1.x : fx2s.y;
    float a = as + adh; a = (a >= 0.f) ? a : NEG_SLOPE * a;
    float e = __expf(a);
    acc.x = fmaf(fx01.x, e, acc.x);
    acc.y = fmaf(fx01.y, e, acc.y);
    acc.z = fmaf(fx2s.x, e, acc.z);
    acc.w += e;
  };
  if (lds_path) {
    unsigned k = kb;
    for (; k + 4 <= ke; k += 4) {
      unsigned i0 = stage_out[k],   i1 = stage_out[k+1];
      unsigned i2 = stage_out[k+2], i3 = stage_out[k+3];
      float4 r0 = xp[i0], r1 = xp[i1], r2 = xp[i2], r3 = xp[i3];
      procr(r0); procr(r1); procr(r2); procr(r3);
    }
    for (; k < ke; ++k) procr(xp[stage_out[k]]);
  } else {
    for (int i = 0; i < size; ++i) {        // correct-but-slow fallback
      unsigned pk = packed2[s0 + i];
      if (((pk >> 17) & 127u) == (unsigned)node) procr(xp[pk & 0x1FFFFu]);
    }
  }
  numx[(size_t)(base + node) * 2 + h] = acc;
}

// -- L1 finalize: reconstruct Wᵀ·numx + self-loop, ReLU, L2 transform, pack -
__global__ void k_node2(const float* __restrict__ x,     // [N,3]
                        const float4* __restrict__ numx, // [N,2]
                        const float* __restrict__ ad1,   // [N,2]
                        const float* __restrict__ w1,    // [3,32]
                        const float* __restrict__ atts1, // [2,16]
                        const float* __restrict__ b1,    // [32]
                        const float* __restrict__ w2,    // [32,14]
                        const float* __restrict__ atts2, // [2,7]
                        const float* __restrict__ attd2, // [2,7]
                        float4* __restrict__ xl2p,       // [N,2] packed head rows
                        float* __restrict__ ad2,         // [N,2]
                        int n) {
  int i = blockIdx.x * blockDim.x + threadIdx.x;
  if (i >= n) return;
  float x0 = x[3*i], x1 = x[3*i+1], x2 = x[3*i+2];
  float v[32];
#pragma unroll
  for (int j = 0; j < 32; ++j)
    v[j] = fmaf(x0, w1[j], fmaf(x1, w1[32+j], x2 * w1[64+j]));
  float s0 = 0.f, s1 = 0.f;
#pragma unroll
  for (int k = 0; k < 16; ++k) {
    s0 = fmaf(v[k],    atts1[k],    s0);
    s1 = fmaf(v[16+k], atts1[16+k], s1);
  }
  float a0 = s0 + ad1[2*i];
  float a1 = s1 + ad1[2*i+1];
  a0 = (a0 >= 0.f) ? a0 : NEG_SLOPE * a0;
  a1 = (a1 >= 0.f) ? a1 : NEG_SLOPE * a1;
  float e0 = __expf(a0), e1 = __expf(a1);
  float4 nx0 = numx[2*i], nx1 = numx[2*i+1];
  float dh0 = nx0.w + e0 + 1e-16f;
  float dh1 = nx1.w + e1 + 1e-16f;
  float inv0 = 1.f / dh0, inv1 = 1.f / dh1;
  float hbuf[32];
#pragma unroll
  for (int j = 0; j < 16; ++j) {
    float nm = fmaf(nx0.x, w1[j], fmaf(nx0.y, w1[32+j], fmaf(nx0.z, w1[64+j], e0 * v[j])));
    float t = nm * inv0 + b1[j];
    hbuf[j] = t > 0.f ? t : 0.f;
  }
#pragma unroll
  for (int j = 0; j < 16; ++j) {
    int jj = 16 + j;
    float nm = fmaf(nx1.x, w1[jj], fmaf(nx1.y, w1[32+jj], fmaf(nx1.z, w1[64+jj], e1 * v[jj])));
    float t = nm * inv1 + b1[jj];
    hbuf[jj] = t > 0.f ? t : 0.f;
  }
  float o[14];
#pragma unroll
  for (int j = 0; j < 14; ++j) o[j] = 0.f;
#pragma unroll
  for (int ch = 0; ch < 32; ++ch) {
#pragma unroll
    for (int j = 0; j < 14; ++j)
      o[j] = fmaf(hbuf[ch], w2[14*ch + j], o[j]);
  }
  float t0=0.f, t1=0.f, d0=0.f, d1=0.f;
#pragma unroll
  for (int k = 0; k < 7; ++k) {
    t0 = fmaf(o[k],   atts2[k],   t0);
    d0 = fmaf(o[k],   attd2[k],   d0);
    t1 = fmaf(o[7+k], atts2[7+k], t1);
    d1 = fmaf(o[7+k], attd2[7+k], d1);
  }
  float4 rA, rB;
  rA.x = __builtin_bit_cast(float, __floats2half2_rn(o[0], o[1]));
  rA.y = __builtin_bit_cast(float, __floats2half2_rn(o[2], o[3]));
  rA.z = __builtin_bit_cast(float, __floats2half2_rn(o[4], o[5]));
  rA.w = __builtin_bit_cast(float, __floats2half2_rn(o[6], t0));
  rB.x = __builtin_bit_cast(float, __floats2half2_rn(o[7], o[8]));
  rB.y = __builtin_bit_cast(float, __floats2half2_rn(o[9], o[10]));
  rB.z = __builtin_bit_cast(float, __floats2half2_rn(o[11], o[12]));
  rB.w = __builtin_bit_cast(float, __floats2half2_rn(o[13], t1));
  xl2p[2*i]   = rA;
  xl2p[2*i+1] = rB;
  ad2[2*i] = d0; ad2[2*i+1] = d1;
}

// -- L2 gather + finalize: 2 lanes/node (1 per head), as packed in row ------
__global__ void k_gather_final(const unsigned* __restrict__ rp,
                               const int* __restrict__ col,
                               const float4* __restrict__ xl2p, // [N,2]
                               const float* __restrict__ ad2,   // [N,2]
                               const float* __restrict__ b2,    // [7]
                               float* __restrict__ out,         // [N,7]
                               int n, int E) {
  int idx = blockIdx.x * blockDim.x + threadIdx.x;
  int d = idx >> 1;
  int h = idx & 1;
  if (d >= n) return;
  float adh = ad2[2*d + h];
  float acc[7] = {0.f,0.f,0.f,0.f,0.f,0.f,0.f};
  float den = 0.f;

  auto proc = [&](float4 r) {
    float2 c01 = h2f(r.x), c23 = h2f(r.y), c45 = h2f(r.z), c6a = h2f(r.w);
    float a = c6a.y + adh; a = (a >= 0.f) ? a : NEG_SLOPE*a;
    float e = __expf(a);
    acc[0] = fmaf(c01.x, e, acc[0]); acc[1] = fmaf(c01.y, e, acc[1]);
    acc[2] = fmaf(c23.x, e, acc[2]); acc[3] = fmaf(c23.y, e, acc[3]);
    acc[4] = fmaf(c45.x, e, acc[4]); acc[5] = fmaf(c45.y, e, acc[5]);
    acc[6] = fmaf(c6a.x, e, acc[6]); den += e;
  };

  unsigned jb = rp[d];
  unsigned je = (d + 1 < n) ? rp[d + 1] : (unsigned)E;
  unsigned j = jb;
  for (; j + 4 <= je; j += 4) {
    int s0 = col[j], s1 = col[j+1], s2 = col[j+2], s3 = col[j+3];
    float4 r0 = xl2p[2*(size_t)s0 + h];
    float4 r1 = xl2p[2*(size_t)s1 + h];
    float4 r2 = xl2p[2*(size_t)s2 + h];
    float4 r3 = xl2p[2*(size_t)s3 + h];
    proc(r0); proc(r1); proc(r2); proc(r3);
  }
  for (; j < je; ++j) proc(xl2p[2*(size_t)col[j] + h]);
  proc(xl2p[2*(size_t)d + h]);   // self-loop

  float inv = 1.f / (den + 1e-16f);
  float v[7];
#pragma unroll
  for (int c = 0; c < 7; ++c) {
    float mine = acc[c] * inv;
    float other = __shfl_xor(mine, 1, 2);      // other head, same node
    v[c] = 0.5f * (mine + other) + b2[c];
  }
  float m = v[0];
#pragma unroll
  for (int c = 1; c < 7; ++c) m = fmaxf(m, v[c]);
  float s = 0.f;
#pragma unroll
  for (int c = 0; c < 7; ++c) s += __expf(v[c] - m);
  float ls = __logf(s);
  float* o = out + (size_t)d * 7;
  if (h == 0) {
    o[0] = v[0]-m-ls; o[1] = v[1]-m-ls; o[2] = v[2]-m-ls; o[3] = v[3]-m-ls;
  } else {
    o[4] = v[4]-m-ls; o[5] = v[5]-m-ls; o[6] = v[6]-m-ls;
  }
}

extern "C" void kernel_launch(void* const* d_in, const int* in_sizes, int n_in,
                              void* d_out, int out_size, void* d_ws, size_t ws_size,
                              hipStream_t stream) {
  const float* x    = (const float*)d_in[0];
  const int*   ei   = (const int*)  d_in[1];
  const float* w1   = (const float*)d_in[2];
  const float* as1w = (const float*)d_in[3];
  const float* ad1w = (const float*)d_in[4];
  const float* b1   = (const float*)d_in[5];
  const float* w2   = (const float*)d_in[6];
  const float* as2w = (const float*)d_in[7];
  const float* ad2w = (const float*)d_in[8];
  const float* b2   = (const float*)d_in[9];
  float* out = (float*)d_out;

  const int n = in_sizes[0] / 3;
  const int E = in_sizes[1] / 2;
  const int* esrc = ei;
  const int* edst = ei + E;
  const int nb = (n + BNODES - 1) >> BUCKET_BITS;   // 782 for n=100000

  const size_t Na = ((size_t)n + 3) & ~(size_t)3;   // 16B-aligned node stride
  float* ws = (float*)d_ws;
  // workspace layout (4-byte units):
  float4* xp    = (float4*)ws;                      //  4Na  packed x+as rows
  float*  ad1   = ws + 4*Na;                        //  2Na
  float4* numx  = (float4*)(ws + 6*Na);             //  8Na
  float4* xl2p  = (float4*)(ws + 14*Na);            //  8Na
  float*  ad2   = ws + 22*Na;                       //  2Na -> 24Na
  unsigned* ctrl   = (unsigned*)(ws + 24*Na);
  unsigned* gcount = ctrl;                          // MAXNB+1
  unsigned* bstart = ctrl + (MAXNB + 1);            // MAXNB+1
  unsigned* bcur   = ctrl + 2*(MAXNB + 1);          // MAXNB+1
  unsigned* sstart = ctrl + 3*(MAXNB + 1);          // MAXSUP+1
  unsigned* scur   = sstart + (MAXSUP + 1);         // MAXSUP
  unsigned* rp     = scur + MAXSUP;                 // Na
  int*      col    = (int*)(rp + Na);               // E
  unsigned* packed2= (unsigned*)(col + E);          // E
  unsigned* tmp1   = packed2 + E;                   // E

  const int nbN = (n + 255) / 256;
  const int nbC = (E + CHUNK - 1) / CHUNK;

  k_node1<<<nbN, 256, 0, stream>>>(x, w1, as1w, ad1w, xp, ad1, gcount, n);

  // two-level radix CSR build (shared by both layers)
  k_hist1024<<<512, 256, 0, stream>>>(edst, gcount, E, nb);
  k_scanall <<<1, MAXNB, 0, stream>>>(gcount, bstart, bcur, sstart, scur, nb);
  k_part1   <<<nbC, PTHREADS, 0, stream>>>(esrc, edst, scur, tmp1, E);
  k_part2   <<<nbC, PTHREADS, 0, stream>>>(tmp1, sstart, bcur, packed2, E, nb);

  // per-bucket sort + fused layer-1 x-space gather (xp table L2-resident)
  k_sortb_g1<<<nb, 256, 0, stream>>>(bstart, packed2, xp, ad1, col, rp, numx, n);

  k_node2<<<nbN, 256, 0, stream>>>(x, numx, ad1, w1, as1w, b1, w2,
                                   as2w, ad2w, xl2p, ad2, n);

  // Layer 2: 2 lanes/node (1 per head), as packed in row (table 3.2 MB)
  k_gather_final<<<(2*n + 255)/256, 256, 0, stream>>>(
      rp, col, xl2p, ad2, b2, out, n, E);
}